// Round 5
// baseline (474.859 us; speedup 1.0000x reference)
//
#include <hip/hip_runtime.h>
#include <hip/hip_bf16.h>

// GCNConv + ReLU: out = relu( (A_norm @ (x W)) + b ), A_norm = D^-1/2 (A + I) D^-1/2
// Round 4b (compile fix: __builtin_nontemporal_store needs a clang ext_vector, not
// HIP's float4 class):
//  - aggregate: column-sliced (8 slices x 32 cols = 64 B/line) + XCD pinning via
//    blockIdx&7: per-XCD working set = 3.2 MB xwp slice < 4 MB L2. csr/row_ptr/out
//    accesses nontemporal so the slice stays resident. One wave per (node,slice):
//    8 col-lanes x 8 edge-groups, butterfly reduce. Was: 107 us, FETCH 355 MB (58% L2 hit).
//  - pass1/pass2 at 1024 threads: pass1 LDS-bound occupancy 12->32 waves/CU,
//    pass2 4x parallelism per bucket.
// GEMM: bf16 MFMA 16x16x32, W pre-transposed; epilogue scales by dinv[row], stores bf16.

#define FEATS 256
#define MAXBUCK 200   // >= (50000+255)>>8 = 196
#define P1_CAP 64     // LDS slots per bucket per 4096-edge chunk (mean ~21)
#define BCAP 10240    // temp capacity per bucket (mean 8192, ~22 sigma)

typedef __bf16 bf16x8 __attribute__((ext_vector_type(8)));
typedef float f32x4 __attribute__((ext_vector_type(4)));

__device__ __forceinline__ unsigned short f2bf(float f) {  // RNE
  unsigned u = __float_as_uint(f);
  u += 0x7fffu + ((u >> 16) & 1u);
  return (unsigned short)(u >> 16);
}
__device__ __forceinline__ float bflo(unsigned u) { return __uint_as_float(u << 16); }
__device__ __forceinline__ float bfhi(unsigned u) { return __uint_as_float(u & 0xFFFF0000u); }

// ---------------- CSR build ----------------

__global__ __launch_bounds__(256) void zero_i32(int* __restrict__ p, int n) {
  int i = blockIdx.x * 256 + threadIdx.x;
  if (i < n) p[i] = 0;
}

// pass1: bin packed edges (dst<<16|src) by dst>>8. 1024 threads, 4096 edges/block.
__global__ __launch_bounds__(1024) void pass1_bin(const int* __restrict__ src,
                                                  const int* __restrict__ dst,
                                                  int E, int nbuck,
                                                  int* __restrict__ gcursor,
                                                  unsigned* __restrict__ temp) {
  __shared__ unsigned lbuf[MAXBUCK * P1_CAP];  // 51.2 KB
  __shared__ int lcnt[MAXBUCK];
  __shared__ int lbase[MAXBUCK];
  const int tid = threadIdx.x;
  for (int i = tid; i < nbuck; i += 1024) lcnt[i] = 0;
  __syncthreads();

  const int e0 = blockIdx.x * 4096;
  #pragma unroll
  for (int i = 0; i < 4; ++i) {
    int e = e0 + i * 1024 + tid;
    if (e < E) {
      unsigned d = (unsigned)dst[e];
      unsigned p = (d << 16) | (unsigned)src[e];
      int b = (int)(d >> 8);
      int pos = atomicAdd(&lcnt[b], 1);
      if (pos < P1_CAP) {
        lbuf[b * P1_CAP + pos] = p;
      } else {  // rare spill: direct global scatter
        int gp = atomicAdd(&gcursor[b], 1);
        temp[(size_t)b * BCAP + gp] = p;
      }
    }
  }
  __syncthreads();
  if (tid < nbuck) {
    int c = lcnt[tid]; if (c > P1_CAP) c = P1_CAP;
    lcnt[tid] = c;
    lbase[tid] = atomicAdd(&gcursor[tid], c);
  }
  __syncthreads();
  for (int i = tid; i < nbuck * P1_CAP; i += 1024) {
    int b = i >> 6, j = i & (P1_CAP - 1);
    if (j < lcnt[b]) temp[(size_t)b * BCAP + lbase[b] + j] = lbuf[i];
  }
}

// exclusive scan over bucket counts (nbuck <= 256), one block
__global__ __launch_bounds__(256) void scan_buckets(const int* __restrict__ gcursor,
                                                    int* __restrict__ bbase,
                                                    int* __restrict__ row_ptr,
                                                    int nbuck, int n) {
  __shared__ int tmp[256];
  int t = threadIdx.x;
  int v = (t < nbuck) ? min(gcursor[t], BCAP) : 0;
  tmp[t] = v;
  __syncthreads();
  #pragma unroll
  for (int off = 1; off < 256; off <<= 1) {
    int x = (t >= off) ? tmp[t - off] : 0;
    __syncthreads();
    tmp[t] += x;
    __syncthreads();
  }
  if (t < nbuck) bbase[t] = tmp[t] - v;
  if (t == 0) row_ptr[n] = tmp[255];
}

// pass2: per-bucket local CSR. 1024 threads.
__global__ __launch_bounds__(1024) void pass2_csr(const unsigned* __restrict__ temp,
                                                  const int* __restrict__ gcursor,
                                                  const int* __restrict__ bbase,
                                                  unsigned short* __restrict__ csr16,
                                                  int* __restrict__ row_ptr,
                                                  float* __restrict__ dinv, int n) {
  __shared__ unsigned ebuf[BCAP];          // 40 KB
  __shared__ unsigned short sorted[BCAP];  // 20 KB
  __shared__ int hist[256], scn[256], sexcl[256], ofs[256];
  const int b = blockIdx.x;
  const int tid = threadIdx.x;
  int cnt = gcursor[b]; if (cnt > BCAP) cnt = BCAP;
  const int base = bbase[b];
  const unsigned* tp = temp + (size_t)b * BCAP;

  if (tid < 256) { hist[tid] = 0; ofs[tid] = 0; }
  for (int i = tid; i < cnt; i += 1024) ebuf[i] = tp[i];
  __syncthreads();
  for (int i = tid; i < cnt; i += 1024) atomicAdd(&hist[(ebuf[i] >> 16) & 255], 1);
  __syncthreads();

  if (tid < 256) scn[tid] = hist[tid];
  __syncthreads();
  #pragma unroll
  for (int off = 1; off < 256; off <<= 1) {
    int x = 0;
    if (tid < 256 && tid >= off) x = scn[tid - off];
    __syncthreads();
    if (tid < 256) scn[tid] += x;
    __syncthreads();
  }
  if (tid < 256) {
    int v = hist[tid];
    int excl = scn[tid] - v;
    sexcl[tid] = excl;
    int node = (b << 8) + tid;
    if (node < n) {
      row_ptr[node] = base + excl;
      dinv[node] = rsqrtf((float)(v + 1));  // +1 self loop
    }
  }
  __syncthreads();

  for (int i = tid; i < cnt; i += 1024) {
    unsigned e = ebuf[i];
    int dl = (int)((e >> 16) & 255);
    int pos = sexcl[dl] + atomicAdd(&ofs[dl], 1);
    sorted[pos] = (unsigned short)(e & 0xFFFFu);
  }
  __syncthreads();
  for (int i = tid; i < cnt; i += 1024) csr16[base + i] = sorted[i];
}

// ---------------- W transpose + bf16 convert: Wt[n][k] = bf16(W[k][n]) ----------------

__global__ __launch_bounds__(256) void wt_build(const float* __restrict__ W,
                                                unsigned short* __restrict__ Wt) {
  int k = blockIdx.x;
  int nn = threadIdx.x;
  Wt[nn * FEATS + k] = f2bf(W[k * FEATS + nn]);
}

// ---------------- MFMA GEMM: xwp[r][:] = bf16( (x @ W)[r][:] * dinv[r] ) ----------------

__global__ __launch_bounds__(256) void gemm_mfma(const float* __restrict__ x,
                                                 const unsigned short* __restrict__ Wt,
                                                 const float* __restrict__ dinv,
                                                 unsigned short* __restrict__ xwp, int M) {
  const int wave = (int)((blockIdx.x * 256 + threadIdx.x) >> 6);
  const int lane = (int)(threadIdx.x & 63);
  const int m0 = wave * 16;
  if (m0 >= M) return;
  const int lm = lane & 15;
  const int quad = lane >> 4;

  int arow = m0 + lm; if (arow >= M) arow = M - 1;
  const float* xrow = x + (size_t)arow * FEATS + quad * 8;
  bf16x8 Afrag[8];
  #pragma unroll
  for (int kc = 0; kc < 8; ++kc) {
    const float4 f0 = *(const float4*)(xrow + kc * 32);
    const float4 f1 = *(const float4*)(xrow + kc * 32 + 4);
    union { bf16x8 v; unsigned short u[8]; } a;
    a.u[0] = f2bf(f0.x); a.u[1] = f2bf(f0.y); a.u[2] = f2bf(f0.z); a.u[3] = f2bf(f0.w);
    a.u[4] = f2bf(f1.x); a.u[5] = f2bf(f1.y); a.u[6] = f2bf(f1.z); a.u[7] = f2bf(f1.w);
    Afrag[kc] = a.v;
  }

  float dsc[4];
  #pragma unroll
  for (int r = 0; r < 4; ++r) {
    int rr = m0 + quad * 4 + r; if (rr >= M) rr = M - 1;
    dsc[r] = dinv[rr];
  }

  for (int ct = 0; ct < 16; ++ct) {
    const int c0 = ct * 16;
    const unsigned short* wrow = Wt + (size_t)(c0 + lm) * FEATS + quad * 8;
    f32x4 acc = {0.f, 0.f, 0.f, 0.f};
    #pragma unroll
    for (int kc = 0; kc < 8; ++kc) {
      bf16x8 B = *(const bf16x8*)(wrow + kc * 32);
      acc = __builtin_amdgcn_mfma_f32_16x16x32_bf16(Afrag[kc], B, acc, 0, 0, 0);
    }
    #pragma unroll
    for (int r = 0; r < 4; ++r) {
      int row = m0 + quad * 4 + r;
      if (row < M) xwp[(size_t)row * FEATS + c0 + lm] = f2bf(acc[r] * dsc[r]);
    }
  }
}

// ---------------- aggregation: column-sliced, XCD-pinned ----------------
// slice = blockIdx&7 (round-robin block->XCD assumed). One wave per (node,slice):
// lanes = 8 col-lanes (uint2 = 4 bf16 = 8 B; 8 lanes cover the 64 B slice line)
//       x 8 edge-groups (8 edges in flight). Butterfly-reduce edge-groups at end.

__global__ __launch_bounds__(256) void aggregate(const unsigned short* __restrict__ xwp,
                                                 const float* __restrict__ dinv,
                                                 const int* __restrict__ row_ptr,
                                                 const unsigned short* __restrict__ csr16,
                                                 const float* __restrict__ bias,
                                                 float* __restrict__ out, int n) {
  const int slice = (int)(blockIdx.x & 7);
  const int node = (int)((blockIdx.x >> 3) * 4 + (threadIdx.x >> 6));
  if (node >= n) return;
  const int lane = (int)(threadIdx.x & 63);
  const int eg = lane >> 3;          // edge group 0..7
  const int cl = lane & 7;           // col lane 0..7
  const int colofs = slice * 32 + cl * 4;  // element offset (ushort in xwp, float in out)

  float a0 = 0.f, a1 = 0.f, a2 = 0.f, a3 = 0.f;

  const int beg = __builtin_nontemporal_load(row_ptr + node);
  const int end = __builtin_nontemporal_load(row_ptr + node + 1);
  for (int base = beg; base < end; base += 16) {
    int i0 = base + eg;
    int i1 = i0 + 8;
    if (i0 < end) {
      int s0 = (int)__builtin_nontemporal_load(csr16 + i0);
      uint2 v = *(const uint2*)(xwp + (((size_t)s0) << 8) + colofs);
      a0 += bflo(v.x); a1 += bfhi(v.x); a2 += bflo(v.y); a3 += bfhi(v.y);
    }
    if (i1 < end) {
      int s1 = (int)__builtin_nontemporal_load(csr16 + i1);
      uint2 v = *(const uint2*)(xwp + (((size_t)s1) << 8) + colofs);
      a0 += bflo(v.x); a1 += bfhi(v.x); a2 += bflo(v.y); a3 += bfhi(v.y);
    }
  }

  // reduce across the 8 edge-groups (lanes with same cl)
  #pragma unroll
  for (int m = 8; m < 64; m <<= 1) {
    a0 += __shfl_xor(a0, m);
    a1 += __shfl_xor(a1, m);
    a2 += __shfl_xor(a2, m);
    a3 += __shfl_xor(a3, m);
  }

  if (eg == 0) {
    // self-loop term (xwp prescaled by dinv[src])
    uint2 sv = *(const uint2*)(xwp + (((size_t)node) << 8) + colofs);
    a0 += bflo(sv.x); a1 += bfhi(sv.x); a2 += bflo(sv.y); a3 += bfhi(sv.y);
    const float dd = dinv[node];
    const float* bp = bias + colofs;
    f32x4 o;
    o.x = fmaxf(fmaf(a0, dd, bp[0]), 0.f);
    o.y = fmaxf(fmaf(a1, dd, bp[1]), 0.f);
    o.z = fmaxf(fmaf(a2, dd, bp[2]), 0.f);
    o.w = fmaxf(fmaf(a3, dd, bp[3]), 0.f);
    __builtin_nontemporal_store(o, (f32x4*)(out + (((size_t)node) << 8) + colofs));
  }
}

// ---------------- launch ----------------

extern "C" void kernel_launch(void* const* d_in, const int* in_sizes, int n_in,
                              void* d_out, int out_size, void* d_ws, size_t ws_size,
                              hipStream_t stream) {
  const float* x  = (const float*)d_in[0];   // [n, 256]
  const int*   ei = (const int*)d_in[1];     // [2, E]
  const float* W  = (const float*)d_in[2];   // [256, 256]
  const float* b  = (const float*)d_in[3];   // [256]

  const int n = in_sizes[0] / FEATS;         // 50000
  const int E = in_sizes[1] / 2;             // 1,600,000
  const int* src = ei;
  const int* dst = ei + E;
  const int nbuck = (n + 255) >> 8;          // 196

  // workspace layout (bytes)
  char* ws = (char*)d_ws;
  unsigned short* xwp   = (unsigned short*)(ws);                 // 25,600,000
  unsigned short* Wt    = (unsigned short*)(ws + 25600000);      //    131,072
  float*          dinv  = (float*)(ws + 25731072);               //    200,000
  int*            row_ptr = (int*)(ws + 25931072);               //    200,064
  unsigned short* csr16 = (unsigned short*)(ws + 26131136);      //  3,200,000
  int*            gcursor = (int*)(ws + 29331136);               //      1,024
  int*            bbase   = (int*)(ws + 29332160);               //      1,024
  unsigned*       temp    = (unsigned*)(ws + 29333184);          //  8,028,160
  // total ~37.4 MB

  hipLaunchKernelGGL(zero_i32, dim3(1), dim3(256), 0, stream, gcursor, nbuck);
  hipLaunchKernelGGL(wt_build, dim3(256), dim3(256), 0, stream, W, Wt);

  const int g_p1 = (E + 4095) / 4096;  // 391
  hipLaunchKernelGGL(pass1_bin, dim3(g_p1), dim3(1024), 0, stream, src, dst, E, nbuck, gcursor, temp);
  hipLaunchKernelGGL(scan_buckets, dim3(1), dim3(256), 0, stream, gcursor, bbase, row_ptr, nbuck, n);
  hipLaunchKernelGGL(pass2_csr, dim3(nbuck), dim3(1024), 0, stream, temp, gcursor, bbase,
                     csr16, row_ptr, dinv, n);

  const int strips = (n + 15) / 16;
  hipLaunchKernelGGL(gemm_mfma, dim3((strips + 3) / 4), dim3(256), 0, stream, x, Wt, dinv, xwp, n);

  const int g_agg = ((n + 3) / 4) * 8;  // (node-chunk, slice) pairs; slice = bid&7
  hipLaunchKernelGGL(aggregate, dim3(g_agg), dim3(256), 0, stream,
                     xwp, dinv, row_ptr, csr16, b, (float*)d_out, n);
}

// Round 6
// 292.399 us; speedup vs baseline: 1.6240x; 1.6240x over previous
//
#include <hip/hip_runtime.h>
#include <hip/hip_bf16.h>

// GCNConv + ReLU: out = relu( (A_norm @ (x W)) + b ), A_norm = D^-1/2 (A + I) D^-1/2
// Round 6: REVERT aggregate to round-3 structure (one wave per dst node, full
// 512 B row per gather, shfl-distributed indices, 8-deep load pipeline).
// Round-5's column-sliced/XCD-pinned variant FAILED: FETCH unchanged (339 MB) =>
// blockIdx&7 does not pin slices to XCD L2s; and MLP dropped 4 KB->1 KB in
// flight per wave => 1.33 TB/s vs 3.9. Kept from round 5: 1024-thread
// pass1/pass2 (~23 us), NT store of the 51 MB output (don't evict xwp from L2).

#define FEATS 256
#define MAXBUCK 200   // >= (50000+255)>>8 = 196
#define P1_CAP 64     // LDS slots per bucket per 4096-edge chunk (mean ~21)
#define BCAP 10240    // temp capacity per bucket (mean 8192, ~22 sigma)

typedef __bf16 bf16x8 __attribute__((ext_vector_type(8)));
typedef float f32x4 __attribute__((ext_vector_type(4)));

__device__ __forceinline__ unsigned short f2bf(float f) {  // RNE
  unsigned u = __float_as_uint(f);
  u += 0x7fffu + ((u >> 16) & 1u);
  return (unsigned short)(u >> 16);
}
__device__ __forceinline__ float bflo(unsigned u) { return __uint_as_float(u << 16); }
__device__ __forceinline__ float bfhi(unsigned u) { return __uint_as_float(u & 0xFFFF0000u); }

// ---------------- CSR build ----------------

__global__ __launch_bounds__(256) void zero_i32(int* __restrict__ p, int n) {
  int i = blockIdx.x * 256 + threadIdx.x;
  if (i < n) p[i] = 0;
}

// pass1: bin packed edges (dst<<16|src) by dst>>8. 1024 threads, 4096 edges/block.
__global__ __launch_bounds__(1024) void pass1_bin(const int* __restrict__ src,
                                                  const int* __restrict__ dst,
                                                  int E, int nbuck,
                                                  int* __restrict__ gcursor,
                                                  unsigned* __restrict__ temp) {
  __shared__ unsigned lbuf[MAXBUCK * P1_CAP];  // 51.2 KB
  __shared__ int lcnt[MAXBUCK];
  __shared__ int lbase[MAXBUCK];
  const int tid = threadIdx.x;
  for (int i = tid; i < nbuck; i += 1024) lcnt[i] = 0;
  __syncthreads();

  const int e0 = blockIdx.x * 4096;
  #pragma unroll
  for (int i = 0; i < 4; ++i) {
    int e = e0 + i * 1024 + tid;
    if (e < E) {
      unsigned d = (unsigned)dst[e];
      unsigned p = (d << 16) | (unsigned)src[e];
      int b = (int)(d >> 8);
      int pos = atomicAdd(&lcnt[b], 1);
      if (pos < P1_CAP) {
        lbuf[b * P1_CAP + pos] = p;
      } else {  // rare spill: direct global scatter
        int gp = atomicAdd(&gcursor[b], 1);
        temp[(size_t)b * BCAP + gp] = p;
      }
    }
  }
  __syncthreads();
  if (tid < nbuck) {
    int c = lcnt[tid]; if (c > P1_CAP) c = P1_CAP;
    lcnt[tid] = c;
    lbase[tid] = atomicAdd(&gcursor[tid], c);
  }
  __syncthreads();
  for (int i = tid; i < nbuck * P1_CAP; i += 1024) {
    int b = i >> 6, j = i & (P1_CAP - 1);
    if (j < lcnt[b]) temp[(size_t)b * BCAP + lbase[b] + j] = lbuf[i];
  }
}

// exclusive scan over bucket counts (nbuck <= 256), one block
__global__ __launch_bounds__(256) void scan_buckets(const int* __restrict__ gcursor,
                                                    int* __restrict__ bbase,
                                                    int* __restrict__ row_ptr,
                                                    int nbuck, int n) {
  __shared__ int tmp[256];
  int t = threadIdx.x;
  int v = (t < nbuck) ? min(gcursor[t], BCAP) : 0;
  tmp[t] = v;
  __syncthreads();
  #pragma unroll
  for (int off = 1; off < 256; off <<= 1) {
    int x = (t >= off) ? tmp[t - off] : 0;
    __syncthreads();
    tmp[t] += x;
    __syncthreads();
  }
  if (t < nbuck) bbase[t] = tmp[t] - v;
  if (t == 0) row_ptr[n] = tmp[255];
}

// pass2: per-bucket local CSR. 1024 threads.
__global__ __launch_bounds__(1024) void pass2_csr(const unsigned* __restrict__ temp,
                                                  const int* __restrict__ gcursor,
                                                  const int* __restrict__ bbase,
                                                  unsigned short* __restrict__ csr16,
                                                  int* __restrict__ row_ptr,
                                                  float* __restrict__ dinv, int n) {
  __shared__ unsigned ebuf[BCAP];          // 40 KB
  __shared__ unsigned short sorted[BCAP];  // 20 KB
  __shared__ int hist[256], scn[256], sexcl[256], ofs[256];
  const int b = blockIdx.x;
  const int tid = threadIdx.x;
  int cnt = gcursor[b]; if (cnt > BCAP) cnt = BCAP;
  const int base = bbase[b];
  const unsigned* tp = temp + (size_t)b * BCAP;

  if (tid < 256) { hist[tid] = 0; ofs[tid] = 0; }
  for (int i = tid; i < cnt; i += 1024) ebuf[i] = tp[i];
  __syncthreads();
  for (int i = tid; i < cnt; i += 1024) atomicAdd(&hist[(ebuf[i] >> 16) & 255], 1);
  __syncthreads();

  if (tid < 256) scn[tid] = hist[tid];
  __syncthreads();
  #pragma unroll
  for (int off = 1; off < 256; off <<= 1) {
    int x = 0;
    if (tid < 256 && tid >= off) x = scn[tid - off];
    __syncthreads();
    if (tid < 256) scn[tid] += x;
    __syncthreads();
  }
  if (tid < 256) {
    int v = hist[tid];
    int excl = scn[tid] - v;
    sexcl[tid] = excl;
    int node = (b << 8) + tid;
    if (node < n) {
      row_ptr[node] = base + excl;
      dinv[node] = rsqrtf((float)(v + 1));  // +1 self loop
    }
  }
  __syncthreads();

  for (int i = tid; i < cnt; i += 1024) {
    unsigned e = ebuf[i];
    int dl = (int)((e >> 16) & 255);
    int pos = sexcl[dl] + atomicAdd(&ofs[dl], 1);
    sorted[pos] = (unsigned short)(e & 0xFFFFu);
  }
  __syncthreads();
  for (int i = tid; i < cnt; i += 1024) csr16[base + i] = sorted[i];
}

// ---------------- W transpose + bf16 convert: Wt[n][k] = bf16(W[k][n]) ----------------

__global__ __launch_bounds__(256) void wt_build(const float* __restrict__ W,
                                                unsigned short* __restrict__ Wt) {
  int k = blockIdx.x;
  int nn = threadIdx.x;
  Wt[nn * FEATS + k] = f2bf(W[k * FEATS + nn]);
}

// ---------------- MFMA GEMM: xwp[r][:] = bf16( (x @ W)[r][:] * dinv[r] ) ----------------

__global__ __launch_bounds__(256) void gemm_mfma(const float* __restrict__ x,
                                                 const unsigned short* __restrict__ Wt,
                                                 const float* __restrict__ dinv,
                                                 unsigned short* __restrict__ xwp, int M) {
  const int wave = (int)((blockIdx.x * 256 + threadIdx.x) >> 6);
  const int lane = (int)(threadIdx.x & 63);
  const int m0 = wave * 16;
  if (m0 >= M) return;
  const int lm = lane & 15;
  const int quad = lane >> 4;

  int arow = m0 + lm; if (arow >= M) arow = M - 1;
  const float* xrow = x + (size_t)arow * FEATS + quad * 8;
  bf16x8 Afrag[8];
  #pragma unroll
  for (int kc = 0; kc < 8; ++kc) {
    const float4 f0 = *(const float4*)(xrow + kc * 32);
    const float4 f1 = *(const float4*)(xrow + kc * 32 + 4);
    union { bf16x8 v; unsigned short u[8]; } a;
    a.u[0] = f2bf(f0.x); a.u[1] = f2bf(f0.y); a.u[2] = f2bf(f0.z); a.u[3] = f2bf(f0.w);
    a.u[4] = f2bf(f1.x); a.u[5] = f2bf(f1.y); a.u[6] = f2bf(f1.z); a.u[7] = f2bf(f1.w);
    Afrag[kc] = a.v;
  }

  float dsc[4];
  #pragma unroll
  for (int r = 0; r < 4; ++r) {
    int rr = m0 + quad * 4 + r; if (rr >= M) rr = M - 1;
    dsc[r] = dinv[rr];
  }

  for (int ct = 0; ct < 16; ++ct) {
    const int c0 = ct * 16;
    const unsigned short* wrow = Wt + (size_t)(c0 + lm) * FEATS + quad * 8;
    f32x4 acc = {0.f, 0.f, 0.f, 0.f};
    #pragma unroll
    for (int kc = 0; kc < 8; ++kc) {
      bf16x8 B = *(const bf16x8*)(wrow + kc * 32);
      acc = __builtin_amdgcn_mfma_f32_16x16x32_bf16(Afrag[kc], B, acc, 0, 0, 0);
    }
    #pragma unroll
    for (int r = 0; r < 4; ++r) {
      int row = m0 + quad * 4 + r;
      if (row < M) xwp[(size_t)row * FEATS + c0 + lm] = f2bf(acc[r] * dsc[r]);
    }
  }
}

// ---------------- aggregation: one wave per dst node (round-3 structure) ----------------

__global__ __launch_bounds__(256) void aggregate(const unsigned short* __restrict__ xwp,
                                                 const float* __restrict__ dinv,
                                                 const int* __restrict__ row_ptr,
                                                 const unsigned short* __restrict__ csr16,
                                                 const float* __restrict__ bias,
                                                 float* __restrict__ out, int n) {
  const int node = (int)((blockIdx.x * blockDim.x + threadIdx.x) >> 6);
  const int lane = (int)(threadIdx.x & 63);
  if (node >= n) return;
  const int co = lane << 2;

  uint2 sv = *(const uint2*)(xwp + (((size_t)node) << 8) + co);
  float4 acc;
  acc.x = bflo(sv.x); acc.y = bfhi(sv.x); acc.z = bflo(sv.y); acc.w = bfhi(sv.y);

  const int beg = row_ptr[node];
  const int end = row_ptr[node + 1];
  for (int base = beg; base < end; base += 64) {
    int idx = base + lane;
    int s = (idx < end) ? (int)csr16[idx] : 0;
    int m = end - base;
    if (m > 64) m = 64;
    int i = 0;
    for (; i + 8 <= m; i += 8) {
      uint2 v[8];
      #pragma unroll
      for (int j = 0; j < 8; ++j) {
        int sj = __shfl(s, i + j);
        v[j] = *(const uint2*)(xwp + (((size_t)sj) << 8) + co);
      }
      #pragma unroll
      for (int j = 0; j < 8; ++j) {
        acc.x += bflo(v[j].x); acc.y += bfhi(v[j].x);
        acc.z += bflo(v[j].y); acc.w += bfhi(v[j].y);
      }
    }
    for (; i < m; ++i) {
      int sj = __shfl(s, i);
      uint2 v = *(const uint2*)(xwp + (((size_t)sj) << 8) + co);
      acc.x += bflo(v.x); acc.y += bfhi(v.x);
      acc.z += bflo(v.y); acc.w += bfhi(v.y);
    }
  }

  const float dd = dinv[node];
  const float* bp = bias + co;
  f32x4 o;
  o.x = fmaxf(fmaf(acc.x, dd, bp[0]), 0.f);
  o.y = fmaxf(fmaf(acc.y, dd, bp[1]), 0.f);
  o.z = fmaxf(fmaf(acc.z, dd, bp[2]), 0.f);
  o.w = fmaxf(fmaf(acc.w, dd, bp[3]), 0.f);
  // NT store: 51 MB output, written once -- keep it out of L2 so xwp stays resident
  __builtin_nontemporal_store(o, (f32x4*)(out + (((size_t)node) << 8) + co));
}

// ---------------- launch ----------------

extern "C" void kernel_launch(void* const* d_in, const int* in_sizes, int n_in,
                              void* d_out, int out_size, void* d_ws, size_t ws_size,
                              hipStream_t stream) {
  const float* x  = (const float*)d_in[0];   // [n, 256]
  const int*   ei = (const int*)d_in[1];     // [2, E]
  const float* W  = (const float*)d_in[2];   // [256, 256]
  const float* b  = (const float*)d_in[3];   // [256]

  const int n = in_sizes[0] / FEATS;         // 50000
  const int E = in_sizes[1] / 2;             // 1,600,000
  const int* src = ei;
  const int* dst = ei + E;
  const int nbuck = (n + 255) >> 8;          // 196

  // workspace layout (bytes)
  char* ws = (char*)d_ws;
  unsigned short* xwp   = (unsigned short*)(ws);                 // 25,600,000
  unsigned short* Wt    = (unsigned short*)(ws + 25600000);      //    131,072
  float*          dinv  = (float*)(ws + 25731072);               //    200,000
  int*            row_ptr = (int*)(ws + 25931072);               //    200,064
  unsigned short* csr16 = (unsigned short*)(ws + 26131136);      //  3,200,000
  int*            gcursor = (int*)(ws + 29331136);               //      1,024
  int*            bbase   = (int*)(ws + 29332160);               //      1,024
  unsigned*       temp    = (unsigned*)(ws + 29333184);          //  8,028,160
  // total ~37.4 MB

  hipLaunchKernelGGL(zero_i32, dim3(1), dim3(256), 0, stream, gcursor, nbuck);
  hipLaunchKernelGGL(wt_build, dim3(256), dim3(256), 0, stream, W, Wt);

  const int g_p1 = (E + 4095) / 4096;  // 391
  hipLaunchKernelGGL(pass1_bin, dim3(g_p1), dim3(1024), 0, stream, src, dst, E, nbuck, gcursor, temp);
  hipLaunchKernelGGL(scan_buckets, dim3(1), dim3(256), 0, stream, gcursor, bbase, row_ptr, nbuck, n);
  hipLaunchKernelGGL(pass2_csr, dim3(nbuck), dim3(1024), 0, stream, temp, gcursor, bbase,
                     csr16, row_ptr, dinv, n);

  const int strips = (n + 15) / 16;
  hipLaunchKernelGGL(gemm_mfma, dim3((strips + 3) / 4), dim3(256), 0, stream, x, Wt, dinv, xwp, n);

  const int g_agg = (n * 64 + 255) / 256;  // one wave per node
  hipLaunchKernelGGL(aggregate, dim3(g_agg), dim3(256), 0, stream,
                     xwp, dinv, row_ptr, csr16, b, (float*)d_out, n);
}